// Round 6
// baseline (900.496 us; speedup 1.0000x reference)
//
#include <hip/hip_runtime.h>
#include <hip/hip_bf16.h>

// ALL float tensors are fp32 buffers (values bf16-quantized by the harness).
// Indices are int32 (proven by R3 odd-word detection). Output is fp32.

// -------- degree histogram over dst --------
__global__ void hist_deg(const int* __restrict__ ei, int E, int* __restrict__ deg) {
    int e = blockIdx.x * blockDim.x + threadIdx.x;
    if (e < E) atomicAdd(&deg[ei[E + e]], 1);
}

__global__ void dinv_k(const int* __restrict__ deg, int N, float* __restrict__ dinv) {
    int v = blockIdx.x * blockDim.x + threadIdx.x;
    if (v < N) dinv[v] = rsqrtf((float)(deg[v] + 1));  // +1 self-loop
}

// -------- exclusive scan deg -> rowptr (single block, chunked Hillis-Steele) --------
__global__ __launch_bounds__(1024)
void scan_rowptr(const int* __restrict__ deg, int N, int* __restrict__ rowptr) {
    __shared__ int smem[1024];
    __shared__ int carry_s;
    if (threadIdx.x == 0) { carry_s = 0; rowptr[0] = 0; }
    __syncthreads();
    for (int base = 0; base < N; base += 1024) {
        int i = base + (int)threadIdx.x;
        int v = (i < N) ? deg[i] : 0;
        smem[threadIdx.x] = v;
        __syncthreads();
        for (int off = 1; off < 1024; off <<= 1) {
            int t = (threadIdx.x >= (unsigned)off) ? smem[threadIdx.x - off] : 0;
            __syncthreads();
            smem[threadIdx.x] += t;
            __syncthreads();
        }
        int carry = carry_s;
        if (i < N) rowptr[i + 1] = smem[threadIdx.x] + carry;
        int newcarry = carry + smem[1023];
        __syncthreads();
        if (threadIdx.x == 0) carry_s = newcarry;
        __syncthreads();
    }
}

// -------- CSR fill --------
__global__ void fill_col(const int* __restrict__ ei, int E, const int* __restrict__ rowptr,
                         int* __restrict__ cursor, int* __restrict__ col) {
    int e = blockIdx.x * blockDim.x + threadIdx.x;
    if (e >= E) return;
    int s = ei[e];
    int d = ei[E + e];
    int p = atomicAdd(&cursor[d], 1);
    col[rowptr[d] + p] = s;
}

// -------- GEMM: g[v,:] = dinv[v] * (h[v,:] @ W);  W JAX layout [128,128] fp32 --------
// 256 threads = 2 nodes x 128 cols; h rows in LDS, W streamed from L2 (64 KB, hot).
__global__ __launch_bounds__(256)
void gemm32(const float* __restrict__ hin, const float* __restrict__ W,
            const float* __restrict__ dinv, int N, float* __restrict__ g)
{
    __shared__ float Hs[2][128];
    int v0 = blockIdx.x * 2;
    {
        int rr = threadIdx.x >> 7, kk = threadIdx.x & 127;
        int vv = v0 + rr;
        Hs[rr][kk] = (vv < N) ? hin[(size_t)vv * 128 + kk] : 0.f;
    }
    __syncthreads();

    int r = threadIdx.x >> 7;
    int n = threadIdx.x & 127;
    int v = v0 + r;
    if (v >= N) return;

    float s = 0.f;
#pragma unroll 8
    for (int k = 0; k < 128; ++k)
        s = fmaf(Hs[r][k], W[k * 128 + n], s);
    g[(size_t)v * 128 + n] = s * dinv[v];
}

// -------- gather: h[v] = [relu](dinv[v]*(g[v] + sum_in g[s]) + bias) --------
// one wave per node; lane handles 2 features (float2)
__global__ __launch_bounds__(256)
void gather32(const float* __restrict__ g, const int* __restrict__ rowptr,
              const int* __restrict__ col, const float* __restrict__ dinv,
              const float* __restrict__ bias, int N, int do_relu, float* __restrict__ hout)
{
    int v = blockIdx.x * 4 + (threadIdx.x >> 6);
    if (v >= N) return;
    int lane = threadIdx.x & 63;
    const float2* gp = (const float2*)g;

    float2 su = gp[(size_t)v * 64 + lane];   // self-loop seed
    float s0 = su.x, s1 = su.y;

    int beg = rowptr[v], end = rowptr[v + 1];
    for (int i = beg; i < end; ++i) {
        float2 u = gp[(size_t)col[i] * 64 + lane];
        s0 += u.x;
        s1 += u.y;
    }
    float dv = dinv[v];
    float2 bb = ((const float2*)bias)[lane];
    float r0 = fmaf(dv, s0, bb.x);
    float r1 = fmaf(dv, s1, bb.y);
    if (do_relu) { r0 = fmaxf(r0, 0.f); r1 = fmaxf(r1, 0.f); }
    float2 res; res.x = r0; res.y = r1;
    ((float2*)hout)[(size_t)v * 64 + lane] = res;
}

// -------- graph boundaries from sorted batch --------
__global__ void bounds_k(const int* __restrict__ batch, int N, int G, int* __restrict__ gstart) {
    int v = blockIdx.x * blockDim.x + threadIdx.x;
    if (v >= N) return;
    int b = batch[v];
    int bprev = (v == 0) ? -1 : batch[v - 1];
    for (int q = bprev + 1; q <= b; ++q) gstart[q] = v;
    if (v == N - 1)
        for (int q = b + 1; q <= G; ++q) gstart[q] = N;
}

// -------- mean pool: one block (128 threads) per graph --------
__global__ __launch_bounds__(128)
void pool32(const float* __restrict__ h, const int* __restrict__ gstart,
            float* __restrict__ pooled)
{
    int gg = blockIdx.x;
    int f = threadIdx.x;
    int s = gstart[gg], e = gstart[gg + 1];
    float acc = 0.f;
    for (int v = s; v < e; ++v) acc += h[(size_t)v * 128 + f];
    float c = (e > s) ? (float)(e - s) : 1.f;
    pooled[gg * 128 + f] = acc / c;
}

// -------- MLP head (JAX layout: Wm1 [128,256], Wm2 [256,768], fp32) --------
__global__ __launch_bounds__(256)
void mlp1_k(const float* __restrict__ pooled, const float* __restrict__ Wm1,
            const float* __restrict__ bm1, float* __restrict__ out1)
{
    __shared__ float Ps[128];
    int gg = blockIdx.x, j = threadIdx.x;
    if (j < 128) Ps[j] = pooled[gg * 128 + j];
    __syncthreads();
    float s = 0.f;
#pragma unroll 4
    for (int k = 0; k < 128; ++k) s = fmaf(Ps[k], Wm1[k * 256 + j], s);
    s += bm1[j];
    out1[gg * 256 + j] = fmaxf(s, 0.f);
}

__global__ __launch_bounds__(768)
void mlp2_k(const float* __restrict__ out1, const float* __restrict__ Wm2,
            const float* __restrict__ bm2, float* __restrict__ out)
{
    __shared__ float Os[256];
    int gg = blockIdx.x, j = threadIdx.x;
    if (j < 256) Os[j] = out1[gg * 256 + j];
    __syncthreads();
    float s = 0.f;
#pragma unroll 4
    for (int k = 0; k < 256; ++k) s = fmaf(Os[k], Wm2[k * 768 + j], s);
    s += bm2[j];
    out[gg * 768 + j] = s;
}

extern "C" void kernel_launch(void* const* d_in, const int* in_sizes, int n_in,
                              void* d_out, int out_size, void* d_ws, size_t ws_size,
                              hipStream_t stream)
{
    const float* x     = (const float*)d_in[0];
    const int*   ei    = (const int*)d_in[1];   // [2,E] int32: src row then dst row
    const int*   batch = (const int*)d_in[2];
    const float *W1 = (const float*)d_in[3],  *bb1 = (const float*)d_in[4];
    const float *W2 = (const float*)d_in[5],  *bb2 = (const float*)d_in[6];
    const float *W3 = (const float*)d_in[7],  *bb3 = (const float*)d_in[8];
    const float *Wm1 = (const float*)d_in[9],  *bm1 = (const float*)d_in[10];
    const float *Wm2 = (const float*)d_in[11], *bm2 = (const float*)d_in[12];

    const int N = in_sizes[2];        // 50000
    const int E = in_sizes[1] / 2;    // 800000
    const int G = out_size / 768;     // 256

    char* wp = (char*)d_ws;
    float* bufA  = (float*)wp; wp += (size_t)N * 128 * 4;   // 25.6 MB (h)
    float* bufB  = (float*)wp; wp += (size_t)N * 128 * 4;   // 25.6 MB (g)
    int*  col    = (int*)wp;   wp += (size_t)E * 4;         // 3.2 MB
    int*  rowptr = (int*)wp;   wp += (size_t)(N + 1) * 4;
    int*  cursor = (int*)wp;   wp += (size_t)N * 4;
    int*  deg    = (int*)wp;   wp += (size_t)N * 4;
    float* dinv  = (float*)wp; wp += (size_t)N * 4;
    int*  gstart = (int*)wp;   wp += (size_t)(G + 1) * 4;
    float* pooled= (float*)wp; wp += (size_t)G * 128 * 4;
    float* out1  = (float*)wp; wp += (size_t)G * 256 * 4;

    hipMemsetAsync(deg, 0, (size_t)N * 4, stream);
    hipMemsetAsync(cursor, 0, (size_t)N * 4, stream);

    // graph structure
    hist_deg<<<(E + 255) / 256, 256, 0, stream>>>(ei, E, deg);
    dinv_k<<<(N + 255) / 256, 256, 0, stream>>>(deg, N, dinv);
    scan_rowptr<<<1, 1024, 0, stream>>>(deg, N, rowptr);
    fill_col<<<(E + 255) / 256, 256, 0, stream>>>(ei, E, rowptr, cursor, col);
    bounds_k<<<(N + 255) / 256, 256, 0, stream>>>(batch, N, G, gstart);

    const int gemm_grid   = (N + 1) / 2;
    const int gather_grid = (N + 3) / 4;

    // layer 1: x -> bufB (g) -> bufA (h)
    gemm32<<<gemm_grid, 256, 0, stream>>>(x, W1, dinv, N, bufB);
    gather32<<<gather_grid, 256, 0, stream>>>(bufB, rowptr, col, dinv, bb1, N, 1, bufA);
    // layer 2
    gemm32<<<gemm_grid, 256, 0, stream>>>(bufA, W2, dinv, N, bufB);
    gather32<<<gather_grid, 256, 0, stream>>>(bufB, rowptr, col, dinv, bb2, N, 1, bufA);
    // layer 3 (no relu)
    gemm32<<<gemm_grid, 256, 0, stream>>>(bufA, W3, dinv, N, bufB);
    gather32<<<gather_grid, 256, 0, stream>>>(bufB, rowptr, col, dinv, bb3, N, 0, bufA);

    // mean pool (deterministic, segment-based)
    pool32<<<G, 128, 0, stream>>>(bufA, gstart, pooled);

    // MLP head
    mlp1_k<<<G, 256, 0, stream>>>(pooled, Wm1, bm1, out1);
    mlp2_k<<<G, 768, 0, stream>>>(out1, Wm2, bm2, (float*)d_out);
}

// Round 7
// 725.676 us; speedup vs baseline: 1.2409x; 1.2409x over previous
//
#include <hip/hip_runtime.h>
#include <hip/hip_bf16.h>

// All float tensors are fp32 buffers (bf16-quantized values). Indices int32.

// -------- degree histogram over dst --------
__global__ void hist_deg(const int* __restrict__ ei, int E, int* __restrict__ deg) {
    int e = blockIdx.x * blockDim.x + threadIdx.x;
    if (e < E) atomicAdd(&deg[ei[E + e]], 1);
}

__global__ void dinv_k(const int* __restrict__ deg, int N, float* __restrict__ dinv) {
    int v = blockIdx.x * blockDim.x + threadIdx.x;
    if (v < N) dinv[v] = rsqrtf((float)(deg[v] + 1));  // +1 self-loop
}

// -------- exclusive scan deg -> rowptr: per-thread slice + one 1024-scan --------
__global__ __launch_bounds__(1024)
void scan_rowptr(const int* __restrict__ deg, int N, int* __restrict__ rowptr) {
    __shared__ int part[1024];
    int per = (N + 1023) / 1024;
    int t = threadIdx.x;
    int lo = t * per, hi = min(lo + per, N);
    int s = 0;
    for (int i = lo; i < hi; ++i) s += deg[i];
    part[t] = s;
    __syncthreads();
    for (int off = 1; off < 1024; off <<= 1) {
        int v = (t >= off) ? part[t - off] : 0;
        __syncthreads();
        part[t] += v;
        __syncthreads();
    }
    int run = (t == 0) ? 0 : part[t - 1];
    for (int i = lo; i < hi; ++i) {
        rowptr[i] = run;
        run += deg[i];
    }
    if (t == 0) rowptr[N] = part[1023];
}

// -------- CSR fill --------
__global__ void fill_col(const int* __restrict__ ei, int E, const int* __restrict__ rowptr,
                         int* __restrict__ cursor, int* __restrict__ col) {
    int e = blockIdx.x * blockDim.x + threadIdx.x;
    if (e >= E) return;
    int s = ei[e];
    int d = ei[E + e];
    int p = atomicAdd(&cursor[d], 1);
    col[rowptr[d] + p] = s;
}

// -------- GEMM: g[v,:] = dinv[v] * (h[v,:] @ W);  W JAX layout [128,128] --------
// Block = 256 threads, 128 rows x 128 cols tile, k tiled by 32.
// Thread (rg,cg) owns an 8x8 register tile: 2 FLOP/LDS-byte -> VALU-bound.
__global__ __launch_bounds__(256)
void gemm32t(const float* __restrict__ hin, const float* __restrict__ W,
             const float* __restrict__ dinv, int N, float* __restrict__ g)
{
    __shared__ float Ht[128][33];   // [row][k], padded
    __shared__ float Wt[32][128];   // [k][col]
    int r0 = blockIdx.x * 128;
    int t = threadIdx.x;
    int rg = t >> 4, cg = t & 15;

    float acc[8][8];
#pragma unroll
    for (int i = 0; i < 8; ++i)
#pragma unroll
        for (int j = 0; j < 8; ++j) acc[i][j] = 0.f;

    for (int kt = 0; kt < 4; ++kt) {
        __syncthreads();
#pragma unroll
        for (int i = 0; i < 16; ++i) {          // Htile: 128x32
            int idx = t + 256 * i;
            int row = idx >> 5, k = idx & 31;
            int gr = r0 + row;
            Ht[row][k] = (gr < N) ? hin[(size_t)gr * 128 + kt * 32 + k] : 0.f;
        }
#pragma unroll
        for (int i = 0; i < 16; ++i) {          // Wtile: 32x128
            int idx = t + 256 * i;
            int k = idx >> 7, n = idx & 127;
            Wt[k][n] = W[(kt * 32 + k) * 128 + n];
        }
        __syncthreads();
#pragma unroll
        for (int k = 0; k < 32; ++k) {
            float a[8], b[8];
#pragma unroll
            for (int i = 0; i < 8; ++i) a[i] = Ht[rg * 8 + i][k];
#pragma unroll
            for (int j = 0; j < 8; ++j) b[j] = Wt[k][cg * 8 + j];
#pragma unroll
            for (int i = 0; i < 8; ++i)
#pragma unroll
                for (int j = 0; j < 8; ++j)
                    acc[i][j] = fmaf(a[i], b[j], acc[i][j]);
        }
    }
#pragma unroll
    for (int i = 0; i < 8; ++i) {
        int row = r0 + rg * 8 + i;
        if (row < N) {
            float dv = dinv[row];
#pragma unroll
            for (int j = 0; j < 8; ++j)
                g[(size_t)row * 128 + cg * 8 + j] = acc[i][j] * dv;
        }
    }
}

// -------- gather: h[v] = [relu](dinv[v]*(g[v] + sum_in g[s]) + bias) --------
// one wave per node, lane = 2 feats; edge loop unrolled x4 for MLP (4 rows in flight)
__global__ __launch_bounds__(256)
void gather32(const float* __restrict__ g, const int* __restrict__ rowptr,
              const int* __restrict__ col, const float* __restrict__ dinv,
              const float* __restrict__ bias, int N, int do_relu, float* __restrict__ hout)
{
    int v = blockIdx.x * 4 + (threadIdx.x >> 6);
    if (v >= N) return;
    int lane = threadIdx.x & 63;
    const float2* gp = (const float2*)g;

    float2 su = gp[(size_t)v * 64 + lane];
    float s0 = su.x, s1 = su.y;

    int beg = rowptr[v], end = rowptr[v + 1];
    int i = beg;
    for (; i + 4 <= end; i += 4) {
        int c0 = col[i], c1 = col[i + 1], c2 = col[i + 2], c3 = col[i + 3];
        float2 u0 = gp[(size_t)c0 * 64 + lane];
        float2 u1 = gp[(size_t)c1 * 64 + lane];
        float2 u2 = gp[(size_t)c2 * 64 + lane];
        float2 u3 = gp[(size_t)c3 * 64 + lane];
        s0 += u0.x + u1.x + u2.x + u3.x;
        s1 += u0.y + u1.y + u2.y + u3.y;
    }
    for (; i < end; ++i) {
        float2 u = gp[(size_t)col[i] * 64 + lane];
        s0 += u.x;
        s1 += u.y;
    }
    float dv = dinv[v];
    float2 bb = ((const float2*)bias)[lane];
    float r0 = fmaf(dv, s0, bb.x);
    float r1 = fmaf(dv, s1, bb.y);
    if (do_relu) { r0 = fmaxf(r0, 0.f); r1 = fmaxf(r1, 0.f); }
    float2 res; res.x = r0; res.y = r1;
    ((float2*)hout)[(size_t)v * 64 + lane] = res;
}

// -------- graph boundaries from sorted batch --------
__global__ void bounds_k(const int* __restrict__ batch, int N, int G, int* __restrict__ gstart) {
    int v = blockIdx.x * blockDim.x + threadIdx.x;
    if (v >= N) return;
    int b = batch[v];
    int bprev = (v == 0) ? -1 : batch[v - 1];
    for (int q = bprev + 1; q <= b; ++q) gstart[q] = v;
    if (v == N - 1)
        for (int q = b + 1; q <= G; ++q) gstart[q] = N;
}

// -------- mean pool --------
__global__ __launch_bounds__(128)
void pool32(const float* __restrict__ h, const int* __restrict__ gstart,
            float* __restrict__ pooled)
{
    int gg = blockIdx.x;
    int f = threadIdx.x;
    int s = gstart[gg], e = gstart[gg + 1];
    float acc = 0.f;
    for (int v = s; v < e; ++v) acc += h[(size_t)v * 128 + f];
    float c = (e > s) ? (float)(e - s) : 1.f;
    pooled[gg * 128 + f] = acc / c;
}

// -------- MLP head (JAX layout: Wm1 [128,256], Wm2 [256,768]) --------
__global__ __launch_bounds__(256)
void mlp1_k(const float* __restrict__ pooled, const float* __restrict__ Wm1,
            const float* __restrict__ bm1, float* __restrict__ out1)
{
    __shared__ float Ps[128];
    int gg = blockIdx.x, j = threadIdx.x;
    if (j < 128) Ps[j] = pooled[gg * 128 + j];
    __syncthreads();
    float s = 0.f;
#pragma unroll 4
    for (int k = 0; k < 128; ++k) s = fmaf(Ps[k], Wm1[k * 256 + j], s);
    s += bm1[j];
    out1[gg * 256 + j] = fmaxf(s, 0.f);
}

__global__ __launch_bounds__(768)
void mlp2_k(const float* __restrict__ out1, const float* __restrict__ Wm2,
            const float* __restrict__ bm2, float* __restrict__ out)
{
    __shared__ float Os[256];
    int gg = blockIdx.x, j = threadIdx.x;
    if (j < 256) Os[j] = out1[gg * 256 + j];
    __syncthreads();
    float s = 0.f;
#pragma unroll 4
    for (int k = 0; k < 256; ++k) s = fmaf(Os[k], Wm2[k * 768 + j], s);
    s += bm2[j];
    out[gg * 768 + j] = s;
}

extern "C" void kernel_launch(void* const* d_in, const int* in_sizes, int n_in,
                              void* d_out, int out_size, void* d_ws, size_t ws_size,
                              hipStream_t stream)
{
    const float* x     = (const float*)d_in[0];
    const int*   ei    = (const int*)d_in[1];   // [2,E] int32: src row then dst row
    const int*   batch = (const int*)d_in[2];
    const float *W1 = (const float*)d_in[3],  *bb1 = (const float*)d_in[4];
    const float *W2 = (const float*)d_in[5],  *bb2 = (const float*)d_in[6];
    const float *W3 = (const float*)d_in[7],  *bb3 = (const float*)d_in[8];
    const float *Wm1 = (const float*)d_in[9],  *bm1 = (const float*)d_in[10];
    const float *Wm2 = (const float*)d_in[11], *bm2 = (const float*)d_in[12];

    const int N = in_sizes[2];        // 50000
    const int E = in_sizes[1] / 2;    // 800000
    const int G = out_size / 768;     // 256

    char* wp = (char*)d_ws;
    float* bufA  = (float*)wp; wp += (size_t)N * 128 * 4;   // 25.6 MB (h)
    float* bufB  = (float*)wp; wp += (size_t)N * 128 * 4;   // 25.6 MB (g)
    int*  col    = (int*)wp;   wp += (size_t)E * 4;         // 3.2 MB
    int*  rowptr = (int*)wp;   wp += (size_t)(N + 1) * 4;
    int*  cursor = (int*)wp;   wp += (size_t)N * 4;
    int*  deg    = (int*)wp;   wp += (size_t)N * 4;
    float* dinv  = (float*)wp; wp += (size_t)N * 4;
    int*  gstart = (int*)wp;   wp += (size_t)(G + 1) * 4;
    float* pooled= (float*)wp; wp += (size_t)G * 128 * 4;
    float* out1  = (float*)wp; wp += (size_t)G * 256 * 4;

    hipMemsetAsync(deg, 0, (size_t)N * 4, stream);
    hipMemsetAsync(cursor, 0, (size_t)N * 4, stream);

    // graph structure
    hist_deg<<<(E + 255) / 256, 256, 0, stream>>>(ei, E, deg);
    dinv_k<<<(N + 255) / 256, 256, 0, stream>>>(deg, N, dinv);
    scan_rowptr<<<1, 1024, 0, stream>>>(deg, N, rowptr);
    fill_col<<<(E + 255) / 256, 256, 0, stream>>>(ei, E, rowptr, cursor, col);
    bounds_k<<<(N + 255) / 256, 256, 0, stream>>>(batch, N, G, gstart);

    const int gemm_grid   = (N + 127) / 128;
    const int gather_grid = (N + 3) / 4;

    // layer 1: x -> bufB (g) -> bufA (h)
    gemm32t<<<gemm_grid, 256, 0, stream>>>(x, W1, dinv, N, bufB);
    gather32<<<gather_grid, 256, 0, stream>>>(bufB, rowptr, col, dinv, bb1, N, 1, bufA);
    // layer 2
    gemm32t<<<gemm_grid, 256, 0, stream>>>(bufA, W2, dinv, N, bufB);
    gather32<<<gather_grid, 256, 0, stream>>>(bufB, rowptr, col, dinv, bb2, N, 1, bufA);
    // layer 3 (no relu)
    gemm32t<<<gemm_grid, 256, 0, stream>>>(bufA, W3, dinv, N, bufB);
    gather32<<<gather_grid, 256, 0, stream>>>(bufB, rowptr, col, dinv, bb3, N, 0, bufA);

    // mean pool
    pool32<<<G, 128, 0, stream>>>(bufA, gstart, pooled);

    // MLP head
    mlp1_k<<<G, 256, 0, stream>>>(pooled, Wm1, bm1, out1);
    mlp2_k<<<G, 768, 0, stream>>>(out1, Wm2, bm2, (float*)d_out);
}

// Round 8
// 509.299 us; speedup vs baseline: 1.7681x; 1.4249x over previous
//
#include <hip/hip_runtime.h>
#include <hip/hip_bf16.h>

using bf16 = __hip_bfloat16;
typedef __attribute__((ext_vector_type(8))) short bf16x8;
typedef __attribute__((ext_vector_type(4))) float f32x4;

__device__ __forceinline__ float lo2f(unsigned u) { return __uint_as_float(u << 16); }
__device__ __forceinline__ float hi2f(unsigned u) { return __uint_as_float(u & 0xffff0000u); }
__device__ __forceinline__ unsigned pack_bf2(float a, float b) {
    bf16 t0 = __float2bfloat16(a), t1 = __float2bfloat16(b);
    return (unsigned)*(unsigned short*)&t0 | ((unsigned)*(unsigned short*)&t1 << 16);
}

// -------- cast fp32 (bf16-valued) -> bf16, lossless --------
__global__ void cast_k(const float* __restrict__ in, int n, bf16* __restrict__ out) {
    int i = blockIdx.x * blockDim.x + threadIdx.x;
    if (i < n) out[i] = __float2bfloat16(in[i]);
}

// -------- degree histogram over dst --------
__global__ void hist_deg(const int* __restrict__ ei, int E, int* __restrict__ deg) {
    int e = blockIdx.x * blockDim.x + threadIdx.x;
    if (e < E) atomicAdd(&deg[ei[E + e]], 1);
}

__global__ void dinv_k(const int* __restrict__ deg, int N, float* __restrict__ dinv) {
    int v = blockIdx.x * blockDim.x + threadIdx.x;
    if (v < N) dinv[v] = rsqrtf((float)(deg[v] + 1));  // +1 self-loop
}

// -------- exclusive scan deg -> rowptr --------
__global__ __launch_bounds__(1024)
void scan_rowptr(const int* __restrict__ deg, int N, int* __restrict__ rowptr) {
    __shared__ int part[1024];
    int per = (N + 1023) / 1024;
    int t = threadIdx.x;
    int lo = t * per, hi = min(lo + per, N);
    int s = 0;
    for (int i = lo; i < hi; ++i) s += deg[i];
    part[t] = s;
    __syncthreads();
    for (int off = 1; off < 1024; off <<= 1) {
        int v = (t >= off) ? part[t - off] : 0;
        __syncthreads();
        part[t] += v;
        __syncthreads();
    }
    int run = (t == 0) ? 0 : part[t - 1];
    for (int i = lo; i < hi; ++i) {
        rowptr[i] = run;
        run += deg[i];
    }
    if (t == 0) rowptr[N] = part[1023];
}

// -------- CSR fill --------
__global__ void fill_col(const int* __restrict__ ei, int E, const int* __restrict__ rowptr,
                         int* __restrict__ cursor, int* __restrict__ col) {
    int e = blockIdx.x * blockDim.x + threadIdx.x;
    if (e >= E) return;
    int s = ei[e];
    int d = ei[E + e];
    int p = atomicAdd(&cursor[d], 1);
    col[rowptr[d] + p] = s;
}

// -------- MFMA GEMM: g[v,:] = dinv[v] * (h[v,:] @ W), bf16 in/out, fp32 accum --------
// W fp32-container [128k][128n]; staged+converted to LDS as Wt[n][k], LDK=136 pad
// (2-way bank aliasing only = free). Block = 4 waves x 16 rows = 64 rows.
#define LDK 136
__global__ __launch_bounds__(256)
void gemm_mfma(const bf16* __restrict__ hin, const float* __restrict__ W,
               const float* __restrict__ dinv, int N, bf16* __restrict__ g)
{
    __shared__ short Wt[128 * LDK];
    for (int i = threadIdx.x; i < 128 * 128; i += 256) {
        int k = i >> 7, n = i & 127;
        bf16 b = __float2bfloat16(W[i]);   // exact: values are bf16-quantized
        Wt[n * LDK + k] = *(short*)&b;
    }
    __syncthreads();

    int wave = threadIdx.x >> 6;
    int lane = threadIdx.x & 63;
    int ln   = lane & 15;
    int quad = lane >> 4;
    int m0 = (blockIdx.x * 4 + wave) * 16;
    if (m0 >= N) return;

    int row = m0 + ln;
    if (row >= N) row = N - 1;   // clamp loads; stores guarded below
    const short* hrow = (const short*)hin + (size_t)row * 128;

    bf16x8 a[4];
#pragma unroll
    for (int kk = 0; kk < 4; ++kk)
        a[kk] = *(const bf16x8*)(hrow + kk * 32 + quad * 8);   // A[m=ln][k=kk*32+quad*8+j]

    f32x4 c[8];
#pragma unroll
    for (int nt = 0; nt < 8; ++nt) c[nt] = (f32x4){0.f, 0.f, 0.f, 0.f};

#pragma unroll
    for (int kk = 0; kk < 4; ++kk) {
#pragma unroll
        for (int nt = 0; nt < 8; ++nt) {
            bf16x8 b = *(const bf16x8*)&Wt[(nt * 16 + ln) * LDK + kk * 32 + quad * 8];
            c[nt] = __builtin_amdgcn_mfma_f32_16x16x32_bf16(a[kk], b, c[nt], 0, 0, 0);
        }
    }

    // C/D: col = lane&15, row = quad*4 + r
#pragma unroll
    for (int r = 0; r < 4; ++r) {
        int m = m0 + quad * 4 + r;
        if (m < N) {
            float dv = dinv[m];
#pragma unroll
            for (int nt = 0; nt < 8; ++nt) {
                bf16 val = __float2bfloat16(c[nt][r] * dv);
                ((unsigned short*)g)[(size_t)m * 128 + nt * 16 + ln] = *(unsigned short*)&val;
            }
        }
    }
}

// -------- gather: h[v] = [relu](dinv[v]*(g[v] + sum_in g[s]) + bias), bf16 g/h --------
// one wave per node, lane = 2 feats (u32 = bf16 pair), fp32 accumulate
__global__ __launch_bounds__(256)
void gather16(const bf16* __restrict__ g, const int* __restrict__ rowptr,
              const int* __restrict__ col, const float* __restrict__ dinv,
              const float* __restrict__ bias, int N, int do_relu, bf16* __restrict__ hout)
{
    int v = blockIdx.x * 4 + (threadIdx.x >> 6);
    if (v >= N) return;
    int lane = threadIdx.x & 63;
    const unsigned* gp = (const unsigned*)g;

    unsigned su = gp[(size_t)v * 64 + lane];    // self-loop seed
    float s0 = lo2f(su), s1 = hi2f(su);

    int beg = rowptr[v], end = rowptr[v + 1];
    int i = beg;
    for (; i + 4 <= end; i += 4) {
        int c0 = col[i], c1 = col[i + 1], c2 = col[i + 2], c3 = col[i + 3];
        unsigned u0 = gp[(size_t)c0 * 64 + lane];
        unsigned u1 = gp[(size_t)c1 * 64 + lane];
        unsigned u2 = gp[(size_t)c2 * 64 + lane];
        unsigned u3 = gp[(size_t)c3 * 64 + lane];
        s0 += lo2f(u0) + lo2f(u1) + lo2f(u2) + lo2f(u3);
        s1 += hi2f(u0) + hi2f(u1) + hi2f(u2) + hi2f(u3);
    }
    for (; i < end; ++i) {
        unsigned u = gp[(size_t)col[i] * 64 + lane];
        s0 += lo2f(u);
        s1 += hi2f(u);
    }
    float dv = dinv[v];
    float2 bb = ((const float2*)bias)[lane];
    float r0 = fmaf(dv, s0, bb.x);
    float r1 = fmaf(dv, s1, bb.y);
    if (do_relu) { r0 = fmaxf(r0, 0.f); r1 = fmaxf(r1, 0.f); }
    ((unsigned*)hout)[(size_t)v * 64 + lane] = pack_bf2(r0, r1);
}

// -------- graph boundaries from sorted batch --------
__global__ void bounds_k(const int* __restrict__ batch, int N, int G, int* __restrict__ gstart) {
    int v = blockIdx.x * blockDim.x + threadIdx.x;
    if (v >= N) return;
    int b = batch[v];
    int bprev = (v == 0) ? -1 : batch[v - 1];
    for (int q = bprev + 1; q <= b; ++q) gstart[q] = v;
    if (v == N - 1)
        for (int q = b + 1; q <= G; ++q) gstart[q] = N;
}

// -------- mean pool over bf16 h --------
__global__ __launch_bounds__(128)
void pool16(const bf16* __restrict__ h, const int* __restrict__ gstart,
            float* __restrict__ pooled)
{
    int gg = blockIdx.x;
    int f = threadIdx.x;
    int s = gstart[gg], e = gstart[gg + 1];
    float acc = 0.f;
    for (int v = s; v < e; ++v)
        acc += __bfloat162float(h[(size_t)v * 128 + f]);
    float c = (e > s) ? (float)(e - s) : 1.f;
    pooled[gg * 128 + f] = acc / c;
}

// -------- MLP head (fp32, tiny) --------
__global__ __launch_bounds__(256)
void mlp1_k(const float* __restrict__ pooled, const float* __restrict__ Wm1,
            const float* __restrict__ bm1, float* __restrict__ out1)
{
    __shared__ float Ps[128];
    int gg = blockIdx.x, j = threadIdx.x;
    if (j < 128) Ps[j] = pooled[gg * 128 + j];
    __syncthreads();
    float s = 0.f;
#pragma unroll 4
    for (int k = 0; k < 128; ++k) s = fmaf(Ps[k], Wm1[k * 256 + j], s);
    s += bm1[j];
    out1[gg * 256 + j] = fmaxf(s, 0.f);
}

__global__ __launch_bounds__(768)
void mlp2_k(const float* __restrict__ out1, const float* __restrict__ Wm2,
            const float* __restrict__ bm2, float* __restrict__ out)
{
    __shared__ float Os[256];
    int gg = blockIdx.x, j = threadIdx.x;
    if (j < 256) Os[j] = out1[gg * 256 + j];
    __syncthreads();
    float s = 0.f;
#pragma unroll 4
    for (int k = 0; k < 256; ++k) s = fmaf(Os[k], Wm2[k * 768 + j], s);
    s += bm2[j];
    out[gg * 768 + j] = s;
}

extern "C" void kernel_launch(void* const* d_in, const int* in_sizes, int n_in,
                              void* d_out, int out_size, void* d_ws, size_t ws_size,
                              hipStream_t stream)
{
    const float* x     = (const float*)d_in[0];
    const int*   ei    = (const int*)d_in[1];   // [2,E] int32: src row then dst row
    const int*   batch = (const int*)d_in[2];
    const float *W1 = (const float*)d_in[3],  *bb1 = (const float*)d_in[4];
    const float *W2 = (const float*)d_in[5],  *bb2 = (const float*)d_in[6];
    const float *W3 = (const float*)d_in[7],  *bb3 = (const float*)d_in[8];
    const float *Wm1 = (const float*)d_in[9],  *bm1 = (const float*)d_in[10];
    const float *Wm2 = (const float*)d_in[11], *bm2 = (const float*)d_in[12];

    const int N = in_sizes[2];        // 50000
    const int E = in_sizes[1] / 2;    // 800000
    const int G = out_size / 768;     // 256

    char* wp = (char*)d_ws;
    bf16* bufX   = (bf16*)wp;  wp += (size_t)N * 128 * 2;   // 12.8 MB (x cast / h)
    bf16* bufG   = (bf16*)wp;  wp += (size_t)N * 128 * 2;   // 12.8 MB (g)
    bf16* bufH   = (bf16*)wp;  wp += (size_t)N * 128 * 2;   // 12.8 MB (h)
    int*  col    = (int*)wp;   wp += (size_t)E * 4;         // 3.2 MB
    int*  rowptr = (int*)wp;   wp += (size_t)(N + 1) * 4;
    int*  cursor = (int*)wp;   wp += (size_t)N * 4;
    int*  deg    = (int*)wp;   wp += (size_t)N * 4;
    float* dinv  = (float*)wp; wp += (size_t)N * 4;
    int*  gstart = (int*)wp;   wp += (size_t)(G + 1) * 4;
    float* pooled= (float*)wp; wp += (size_t)G * 128 * 4;
    float* out1  = (float*)wp; wp += (size_t)G * 256 * 4;

    hipMemsetAsync(deg, 0, (size_t)N * 4, stream);
    hipMemsetAsync(cursor, 0, (size_t)N * 4, stream);

    // graph structure + input cast
    hist_deg<<<(E + 255) / 256, 256, 0, stream>>>(ei, E, deg);
    dinv_k<<<(N + 255) / 256, 256, 0, stream>>>(deg, N, dinv);
    scan_rowptr<<<1, 1024, 0, stream>>>(deg, N, rowptr);
    fill_col<<<(E + 255) / 256, 256, 0, stream>>>(ei, E, rowptr, cursor, col);
    bounds_k<<<(N + 255) / 256, 256, 0, stream>>>(batch, N, G, gstart);
    cast_k<<<(N * 128 + 255) / 256, 256, 0, stream>>>(x, N * 128, bufX);

    const int gemm_grid   = (N + 63) / 64;
    const int gather_grid = (N + 3) / 4;

    // layer 1: bufX -> bufG -> bufH
    gemm_mfma<<<gemm_grid, 256, 0, stream>>>(bufX, W1, dinv, N, bufG);
    gather16<<<gather_grid, 256, 0, stream>>>(bufG, rowptr, col, dinv, bb1, N, 1, bufH);
    // layer 2: bufH -> bufG -> bufX (reuse)
    gemm_mfma<<<gemm_grid, 256, 0, stream>>>(bufH, W2, dinv, N, bufG);
    gather16<<<gather_grid, 256, 0, stream>>>(bufG, rowptr, col, dinv, bb2, N, 1, bufX);
    // layer 3 (no relu): bufX -> bufG -> bufH
    gemm_mfma<<<gemm_grid, 256, 0, stream>>>(bufX, W3, dinv, N, bufG);
    gather16<<<gather_grid, 256, 0, stream>>>(bufG, rowptr, col, dinv, bb3, N, 0, bufH);

    // mean pool
    pool16<<<G, 128, 0, stream>>>(bufH, gstart, pooled);

    // MLP head
    mlp1_k<<<G, 256, 0, stream>>>(pooled, Wm1, bm1, out1);
    mlp2_k<<<G, 768, 0, stream>>>(out1, Wm2, bm2, (float*)d_out);
}

// Round 9
// 440.917 us; speedup vs baseline: 2.0423x; 1.1551x over previous
//
#include <hip/hip_runtime.h>
#include <hip/hip_bf16.h>

using bf16 = __hip_bfloat16;
typedef __attribute__((ext_vector_type(8))) short bf16x8;
typedef __attribute__((ext_vector_type(4))) float f32x4;

__device__ __forceinline__ float lo2f(unsigned u) { return __uint_as_float(u << 16); }
__device__ __forceinline__ float hi2f(unsigned u) { return __uint_as_float(u & 0xffff0000u); }
__device__ __forceinline__ unsigned pack_bf2(float a, float b) {
    bf16 t0 = __float2bfloat16(a), t1 = __float2bfloat16(b);
    return (unsigned)*(unsigned short*)&t0 | ((unsigned)*(unsigned short*)&t1 << 16);
}

// -------- cast fp32 (bf16-valued) -> bf16, lossless --------
__global__ void cast_k(const float* __restrict__ in, int n, bf16* __restrict__ out) {
    int i = blockIdx.x * blockDim.x + threadIdx.x;
    if (i < n) out[i] = __float2bfloat16(in[i]);
}

// -------- degree histogram over dst --------
__global__ void hist_deg(const int* __restrict__ ei, int E, int* __restrict__ deg) {
    int e = blockIdx.x * blockDim.x + threadIdx.x;
    if (e < E) atomicAdd(&deg[ei[E + e]], 1);
}

__global__ void dinv_k(const int* __restrict__ deg, int N, float* __restrict__ dinv) {
    int v = blockIdx.x * blockDim.x + threadIdx.x;
    if (v < N) dinv[v] = rsqrtf((float)(deg[v] + 1));  // +1 self-loop
}

// -------- device-wide exclusive scan, 3 kernels (coalesced, parallel) --------
// scan1: per-block local exclusive scan of 256 elems + block sum
__global__ __launch_bounds__(256)
void scan1(const int* __restrict__ deg, int N, int* __restrict__ rowptr,
           int* __restrict__ bsum) {
    __shared__ int sm[256];
    int t = threadIdx.x;
    int i = blockIdx.x * 256 + t;
    int v = (i < N) ? deg[i] : 0;
    sm[t] = v;
    __syncthreads();
#pragma unroll
    for (int off = 1; off < 256; off <<= 1) {
        int x = (t >= off) ? sm[t - off] : 0;
        __syncthreads();
        sm[t] += x;
        __syncthreads();
    }
    if (i < N) rowptr[i] = sm[t] - v;          // local exclusive
    if (t == 255) bsum[blockIdx.x] = sm[255];  // block total
}

// scan2: exclusive scan of block sums (B <= 256) + write rowptr[N] = grand total
__global__ __launch_bounds__(256)
void scan2(int* __restrict__ bsum, int B, int N, int* __restrict__ rowptr) {
    __shared__ int sm[256];
    int t = threadIdx.x;
    int v = (t < B) ? bsum[t] : 0;
    sm[t] = v;
    __syncthreads();
#pragma unroll
    for (int off = 1; off < 256; off <<= 1) {
        int x = (t >= off) ? sm[t - off] : 0;
        __syncthreads();
        sm[t] += x;
        __syncthreads();
    }
    if (t < B) bsum[t] = sm[t] - v;            // exclusive block offsets
    if (t == 255) rowptr[N] = sm[255];         // grand total (= E)
}

// scan3: add block offsets
__global__ __launch_bounds__(256)
void scan3(int N, const int* __restrict__ bsum, int* __restrict__ rowptr) {
    int i = blockIdx.x * 256 + threadIdx.x;
    if (i < N) rowptr[i] += bsum[blockIdx.x];
}

// -------- CSR fill --------
__global__ void fill_col(const int* __restrict__ ei, int E, const int* __restrict__ rowptr,
                         int* __restrict__ cursor, int* __restrict__ col) {
    int e = blockIdx.x * blockDim.x + threadIdx.x;
    if (e >= E) return;
    int s = ei[e];
    int d = ei[E + e];
    int p = atomicAdd(&cursor[d], 1);
    col[rowptr[d] + p] = s;
}

// -------- MFMA GEMM: g[v,:] = dinv[v] * (h[v,:] @ W), bf16 in/out, fp32 accum --------
#define LDK 136
__global__ __launch_bounds__(256)
void gemm_mfma(const bf16* __restrict__ hin, const float* __restrict__ W,
               const float* __restrict__ dinv, int N, bf16* __restrict__ g)
{
    __shared__ short Wt[128 * LDK];
    for (int i = threadIdx.x; i < 128 * 128; i += 256) {
        int k = i >> 7, n = i & 127;
        bf16 b = __float2bfloat16(W[i]);   // exact: values are bf16-quantized
        Wt[n * LDK + k] = *(short*)&b;
    }
    __syncthreads();

    int wave = threadIdx.x >> 6;
    int lane = threadIdx.x & 63;
    int ln   = lane & 15;
    int quad = lane >> 4;
    int m0 = (blockIdx.x * 4 + wave) * 16;
    if (m0 >= N) return;

    int row = m0 + ln;
    if (row >= N) row = N - 1;
    const short* hrow = (const short*)hin + (size_t)row * 128;

    bf16x8 a[4];
#pragma unroll
    for (int kk = 0; kk < 4; ++kk)
        a[kk] = *(const bf16x8*)(hrow + kk * 32 + quad * 8);

    f32x4 c[8];
#pragma unroll
    for (int nt = 0; nt < 8; ++nt) c[nt] = (f32x4){0.f, 0.f, 0.f, 0.f};

#pragma unroll
    for (int kk = 0; kk < 4; ++kk) {
#pragma unroll
        for (int nt = 0; nt < 8; ++nt) {
            bf16x8 b = *(const bf16x8*)&Wt[(nt * 16 + ln) * LDK + kk * 32 + quad * 8];
            c[nt] = __builtin_amdgcn_mfma_f32_16x16x32_bf16(a[kk], b, c[nt], 0, 0, 0);
        }
    }

#pragma unroll
    for (int r = 0; r < 4; ++r) {
        int m = m0 + quad * 4 + r;
        if (m < N) {
            float dv = dinv[m];
#pragma unroll
            for (int nt = 0; nt < 8; ++nt) {
                bf16 val = __float2bfloat16(c[nt][r] * dv);
                ((unsigned short*)g)[(size_t)m * 128 + nt * 16 + ln] = *(unsigned short*)&val;
            }
        }
    }
}

// -------- gather: h[v] = [relu](dinv[v]*(g[v] + sum_in g[s]) + bias), bf16 g/h --------
__global__ __launch_bounds__(256)
void gather16(const bf16* __restrict__ g, const int* __restrict__ rowptr,
              const int* __restrict__ col, const float* __restrict__ dinv,
              const float* __restrict__ bias, int N, int do_relu, bf16* __restrict__ hout)
{
    int v = blockIdx.x * 4 + (threadIdx.x >> 6);
    if (v >= N) return;
    int lane = threadIdx.x & 63;
    const unsigned* gp = (const unsigned*)g;

    unsigned su = gp[(size_t)v * 64 + lane];
    float s0 = lo2f(su), s1 = hi2f(su);

    int beg = rowptr[v], end = rowptr[v + 1];
    int i = beg;
    for (; i + 4 <= end; i += 4) {
        int c0 = col[i], c1 = col[i + 1], c2 = col[i + 2], c3 = col[i + 3];
        unsigned u0 = gp[(size_t)c0 * 64 + lane];
        unsigned u1 = gp[(size_t)c1 * 64 + lane];
        unsigned u2 = gp[(size_t)c2 * 64 + lane];
        unsigned u3 = gp[(size_t)c3 * 64 + lane];
        s0 += lo2f(u0) + lo2f(u1) + lo2f(u2) + lo2f(u3);
        s1 += hi2f(u0) + hi2f(u1) + hi2f(u2) + hi2f(u3);
    }
    for (; i < end; ++i) {
        unsigned u = gp[(size_t)col[i] * 64 + lane];
        s0 += lo2f(u);
        s1 += hi2f(u);
    }
    float dv = dinv[v];
    float2 bb = ((const float2*)bias)[lane];
    float r0 = fmaf(dv, s0, bb.x);
    float r1 = fmaf(dv, s1, bb.y);
    if (do_relu) { r0 = fmaxf(r0, 0.f); r1 = fmaxf(r1, 0.f); }
    ((unsigned*)hout)[(size_t)v * 64 + lane] = pack_bf2(r0, r1);
}

// -------- graph boundaries from sorted batch --------
__global__ void bounds_k(const int* __restrict__ batch, int N, int G, int* __restrict__ gstart) {
    int v = blockIdx.x * blockDim.x + threadIdx.x;
    if (v >= N) return;
    int b = batch[v];
    int bprev = (v == 0) ? -1 : batch[v - 1];
    for (int q = bprev + 1; q <= b; ++q) gstart[q] = v;
    if (v == N - 1)
        for (int q = b + 1; q <= G; ++q) gstart[q] = N;
}

// -------- mean pool over bf16 h --------
__global__ __launch_bounds__(128)
void pool16(const bf16* __restrict__ h, const int* __restrict__ gstart,
            float* __restrict__ pooled)
{
    int gg = blockIdx.x;
    int f = threadIdx.x;
    int s = gstart[gg], e = gstart[gg + 1];
    float acc = 0.f;
    for (int v = s; v < e; ++v)
        acc += __bfloat162float(h[(size_t)v * 128 + f]);
    float c = (e > s) ? (float)(e - s) : 1.f;
    pooled[gg * 128 + f] = acc / c;
}

// -------- MLP head (fp32, tiny) --------
__global__ __launch_bounds__(256)
void mlp1_k(const float* __restrict__ pooled, const float* __restrict__ Wm1,
            const float* __restrict__ bm1, float* __restrict__ out1)
{
    __shared__ float Ps[128];
    int gg = blockIdx.x, j = threadIdx.x;
    if (j < 128) Ps[j] = pooled[gg * 128 + j];
    __syncthreads();
    float s = 0.f;
#pragma unroll 4
    for (int k = 0; k < 128; ++k) s = fmaf(Ps[k], Wm1[k * 256 + j], s);
    s += bm1[j];
    out1[gg * 256 + j] = fmaxf(s, 0.f);
}

__global__ __launch_bounds__(768)
void mlp2_k(const float* __restrict__ out1, const float* __restrict__ Wm2,
            const float* __restrict__ bm2, float* __restrict__ out)
{
    __shared__ float Os[256];
    int gg = blockIdx.x, j = threadIdx.x;
    if (j < 256) Os[j] = out1[gg * 256 + j];
    __syncthreads();
    float s = 0.f;
#pragma unroll 4
    for (int k = 0; k < 256; ++k) s = fmaf(Os[k], Wm2[k * 768 + j], s);
    s += bm2[j];
    out[gg * 768 + j] = s;
}

extern "C" void kernel_launch(void* const* d_in, const int* in_sizes, int n_in,
                              void* d_out, int out_size, void* d_ws, size_t ws_size,
                              hipStream_t stream)
{
    const float* x     = (const float*)d_in[0];
    const int*   ei    = (const int*)d_in[1];   // [2,E] int32: src row then dst row
    const int*   batch = (const int*)d_in[2];
    const float *W1 = (const float*)d_in[3],  *bb1 = (const float*)d_in[4];
    const float *W2 = (const float*)d_in[5],  *bb2 = (const float*)d_in[6];
    const float *W3 = (const float*)d_in[7],  *bb3 = (const float*)d_in[8];
    const float *Wm1 = (const float*)d_in[9],  *bm1 = (const float*)d_in[10];
    const float *Wm2 = (const float*)d_in[11], *bm2 = (const float*)d_in[12];

    const int N = in_sizes[2];        // 50000
    const int E = in_sizes[1] / 2;    // 800000
    const int G = out_size / 768;     // 256

    char* wp = (char*)d_ws;
    bf16* bufX   = (bf16*)wp;  wp += (size_t)N * 128 * 2;   // 12.8 MB
    bf16* bufG   = (bf16*)wp;  wp += (size_t)N * 128 * 2;   // 12.8 MB
    bf16* bufH   = (bf16*)wp;  wp += (size_t)N * 128 * 2;   // 12.8 MB
    int*  col    = (int*)wp;   wp += (size_t)E * 4;         // 3.2 MB
    int*  rowptr = (int*)wp;   wp += (size_t)(N + 1) * 4;
    int*  cursor = (int*)wp;   wp += (size_t)N * 4;
    int*  deg    = (int*)wp;   wp += (size_t)N * 4;
    float* dinv  = (float*)wp; wp += (size_t)N * 4;
    int*  gstart = (int*)wp;   wp += (size_t)(G + 1) * 4;
    float* pooled= (float*)wp; wp += (size_t)G * 128 * 4;
    float* out1  = (float*)wp; wp += (size_t)G * 256 * 4;
    int*  bsum   = (int*)wp;   wp += 256 * 4;

    hipMemsetAsync(deg, 0, (size_t)N * 4, stream);
    hipMemsetAsync(cursor, 0, (size_t)N * 4, stream);

    const int SB = (N + 255) / 256;   // scan blocks (196 <= 256)

    // graph structure + input cast
    hist_deg<<<(E + 255) / 256, 256, 0, stream>>>(ei, E, deg);
    dinv_k<<<(N + 255) / 256, 256, 0, stream>>>(deg, N, dinv);
    scan1<<<SB, 256, 0, stream>>>(deg, N, rowptr, bsum);
    scan2<<<1, 256, 0, stream>>>(bsum, SB, N, rowptr);
    scan3<<<SB, 256, 0, stream>>>(N, bsum, rowptr);
    fill_col<<<(E + 255) / 256, 256, 0, stream>>>(ei, E, rowptr, cursor, col);
    bounds_k<<<(N + 255) / 256, 256, 0, stream>>>(batch, N, G, gstart);
    cast_k<<<(N * 128 + 255) / 256, 256, 0, stream>>>(x, N * 128, bufX);

    const int gemm_grid   = (N + 63) / 64;
    const int gather_grid = (N + 3) / 4;

    // layer 1: bufX -> bufG -> bufH
    gemm_mfma<<<gemm_grid, 256, 0, stream>>>(bufX, W1, dinv, N, bufG);
    gather16<<<gather_grid, 256, 0, stream>>>(bufG, rowptr, col, dinv, bb1, N, 1, bufH);
    // layer 2: bufH -> bufG -> bufX (reuse)
    gemm_mfma<<<gemm_grid, 256, 0, stream>>>(bufH, W2, dinv, N, bufG);
    gather16<<<gather_grid, 256, 0, stream>>>(bufG, rowptr, col, dinv, bb2, N, 1, bufX);
    // layer 3 (no relu): bufX -> bufG -> bufH
    gemm_mfma<<<gemm_grid, 256, 0, stream>>>(bufX, W3, dinv, N, bufG);
    gather16<<<gather_grid, 256, 0, stream>>>(bufG, rowptr, col, dinv, bb3, N, 0, bufH);

    // mean pool
    pool16<<<G, 128, 0, stream>>>(bufH, gstart, pooled);

    // MLP head
    mlp1_k<<<G, 256, 0, stream>>>(pooled, Wm1, bm1, out1);
    mlp2_k<<<G, 768, 0, stream>>>(out1, Wm2, bm2, (float*)d_out);
}

// Round 10
// 405.038 us; speedup vs baseline: 2.2232x; 1.0886x over previous
//
#include <hip/hip_runtime.h>
#include <hip/hip_bf16.h>

using bf16 = __hip_bfloat16;
typedef __attribute__((ext_vector_type(8))) short bf16x8;
typedef __attribute__((ext_vector_type(4))) float f32x4;

__device__ __forceinline__ float lo2f(unsigned u) { return __uint_as_float(u << 16); }
__device__ __forceinline__ float hi2f(unsigned u) { return __uint_as_float(u & 0xffff0000u); }
__device__ __forceinline__ unsigned pack_bf2(float a, float b) {
    bf16 t0 = __float2bfloat16(a), t1 = __float2bfloat16(b);
    return (unsigned)*(unsigned short*)&t0 | ((unsigned)*(unsigned short*)&t1 << 16);
}

// -------- cast fp32 (bf16-valued) -> bf16, lossless --------
__global__ void cast_k(const float* __restrict__ in, int n, bf16* __restrict__ out) {
    int i = blockIdx.x * blockDim.x + threadIdx.x;
    if (i < n) out[i] = __float2bfloat16(in[i]);
}

// -------- degree histogram over dst --------
__global__ void hist_deg(const int* __restrict__ ei, int E, int* __restrict__ deg) {
    int e = blockIdx.x * blockDim.x + threadIdx.x;
    if (e < E) atomicAdd(&deg[ei[E + e]], 1);
}

__global__ void dinv_k(const int* __restrict__ deg, int N, float* __restrict__ dinv) {
    int v = blockIdx.x * blockDim.x + threadIdx.x;
    if (v < N) dinv[v] = rsqrtf((float)(deg[v] + 1));  // +1 self-loop
}

// -------- device-wide exclusive scan, 3 kernels --------
__global__ __launch_bounds__(256)
void scan1(const int* __restrict__ deg, int N, int* __restrict__ rowptr,
           int* __restrict__ bsum) {
    __shared__ int sm[256];
    int t = threadIdx.x;
    int i = blockIdx.x * 256 + t;
    int v = (i < N) ? deg[i] : 0;
    sm[t] = v;
    __syncthreads();
#pragma unroll
    for (int off = 1; off < 256; off <<= 1) {
        int x = (t >= off) ? sm[t - off] : 0;
        __syncthreads();
        sm[t] += x;
        __syncthreads();
    }
    if (i < N) rowptr[i] = sm[t] - v;
    if (t == 255) bsum[blockIdx.x] = sm[255];
}

__global__ __launch_bounds__(256)
void scan2(int* __restrict__ bsum, int B, int N, int* __restrict__ rowptr) {
    __shared__ int sm[256];
    int t = threadIdx.x;
    int v = (t < B) ? bsum[t] : 0;
    sm[t] = v;
    __syncthreads();
#pragma unroll
    for (int off = 1; off < 256; off <<= 1) {
        int x = (t >= off) ? sm[t - off] : 0;
        __syncthreads();
        sm[t] += x;
        __syncthreads();
    }
    if (t < B) bsum[t] = sm[t] - v;
    if (t == 255) rowptr[N] = sm[255];
}

__global__ __launch_bounds__(256)
void scan3(int N, const int* __restrict__ bsum, int* __restrict__ rowptr) {
    int i = blockIdx.x * 256 + threadIdx.x;
    if (i < N) rowptr[i] += bsum[blockIdx.x];
}

// -------- CSR fill --------
__global__ void fill_col(const int* __restrict__ ei, int E, const int* __restrict__ rowptr,
                         int* __restrict__ cursor, int* __restrict__ col) {
    int e = blockIdx.x * blockDim.x + threadIdx.x;
    if (e >= E) return;
    int s = ei[e];
    int d = ei[E + e];
    int p = atomicAdd(&cursor[d], 1);
    col[rowptr[d] + p] = s;
}

// -------- MFMA GEMM: g[v,:] = dinv[v] * (h[v,:] @ W), bf16 in/out, fp32 accum --------
#define LDK 136
__global__ __launch_bounds__(256)
void gemm_mfma(const bf16* __restrict__ hin, const float* __restrict__ W,
               const float* __restrict__ dinv, int N, bf16* __restrict__ g)
{
    __shared__ short Wt[128 * LDK];
    for (int i = threadIdx.x; i < 128 * 128; i += 256) {
        int k = i >> 7, n = i & 127;
        bf16 b = __float2bfloat16(W[i]);   // exact: values are bf16-quantized
        Wt[n * LDK + k] = *(short*)&b;
    }
    __syncthreads();

    int wave = threadIdx.x >> 6;
    int lane = threadIdx.x & 63;
    int ln   = lane & 15;
    int quad = lane >> 4;
    int m0 = (blockIdx.x * 4 + wave) * 16;
    if (m0 >= N) return;

    int row = m0 + ln;
    if (row >= N) row = N - 1;
    const short* hrow = (const short*)hin + (size_t)row * 128;

    bf16x8 a[4];
#pragma unroll
    for (int kk = 0; kk < 4; ++kk)
        a[kk] = *(const bf16x8*)(hrow + kk * 32 + quad * 8);

    f32x4 c[8];
#pragma unroll
    for (int nt = 0; nt < 8; ++nt) c[nt] = (f32x4){0.f, 0.f, 0.f, 0.f};

#pragma unroll
    for (int kk = 0; kk < 4; ++kk) {
#pragma unroll
        for (int nt = 0; nt < 8; ++nt) {
            bf16x8 b = *(const bf16x8*)&Wt[(nt * 16 + ln) * LDK + kk * 32 + quad * 8];
            c[nt] = __builtin_amdgcn_mfma_f32_16x16x32_bf16(a[kk], b, c[nt], 0, 0, 0);
        }
    }

#pragma unroll
    for (int r = 0; r < 4; ++r) {
        int m = m0 + quad * 4 + r;
        if (m < N) {
            float dv = dinv[m];
#pragma unroll
            for (int nt = 0; nt < 8; ++nt) {
                bf16 val = __float2bfloat16(c[nt][r] * dv);
                ((unsigned short*)g)[(size_t)m * 128 + nt * 16 + ln] = *(unsigned short*)&val;
            }
        }
    }
}

// -------- gather: h[v] = [relu](dinv[v]*(g[v] + sum_in g[s]) + bias), bf16 g/h --------
__global__ __launch_bounds__(256)
void gather16(const bf16* __restrict__ g, const int* __restrict__ rowptr,
              const int* __restrict__ col, const float* __restrict__ dinv,
              const float* __restrict__ bias, int N, int do_relu, bf16* __restrict__ hout)
{
    int v = blockIdx.x * 4 + (threadIdx.x >> 6);
    if (v >= N) return;
    int lane = threadIdx.x & 63;
    const unsigned* gp = (const unsigned*)g;

    unsigned su = gp[(size_t)v * 64 + lane];
    float s0 = lo2f(su), s1 = hi2f(su);

    int beg = rowptr[v], end = rowptr[v + 1];
    int i = beg;
    for (; i + 4 <= end; i += 4) {
        int c0 = col[i], c1 = col[i + 1], c2 = col[i + 2], c3 = col[i + 3];
        unsigned u0 = gp[(size_t)c0 * 64 + lane];
        unsigned u1 = gp[(size_t)c1 * 64 + lane];
        unsigned u2 = gp[(size_t)c2 * 64 + lane];
        unsigned u3 = gp[(size_t)c3 * 64 + lane];
        s0 += lo2f(u0) + lo2f(u1) + lo2f(u2) + lo2f(u3);
        s1 += hi2f(u0) + hi2f(u1) + hi2f(u2) + hi2f(u3);
    }
    for (; i < end; ++i) {
        unsigned u = gp[(size_t)col[i] * 64 + lane];
        s0 += lo2f(u);
        s1 += hi2f(u);
    }
    float dv = dinv[v];
    float2 bb = ((const float2*)bias)[lane];
    float r0 = fmaf(dv, s0, bb.x);
    float r1 = fmaf(dv, s1, bb.y);
    if (do_relu) { r0 = fmaxf(r0, 0.f); r1 = fmaxf(r1, 0.f); }
    ((unsigned*)hout)[(size_t)v * 64 + lane] = pack_bf2(r0, r1);
}

// -------- graph boundaries from sorted batch --------
__global__ void bounds_k(const int* __restrict__ batch, int N, int G, int* __restrict__ gstart) {
    int v = blockIdx.x * blockDim.x + threadIdx.x;
    if (v >= N) return;
    int b = batch[v];
    int bprev = (v == 0) ? -1 : batch[v - 1];
    for (int q = bprev + 1; q <= b; ++q) gstart[q] = v;
    if (v == N - 1)
        for (int q = b + 1; q <= G; ++q) gstart[q] = N;
}

// -------- parallel mean pool, stage 1: chunked partial sums + run-flush atomics --------
#define PCH 32   // nodes per block
__global__ __launch_bounds__(128)
void pool_part(const bf16* __restrict__ h, const int* __restrict__ batch, int N,
               float* __restrict__ pooled)
{
    int c0 = blockIdx.x * PCH;
    if (c0 >= N) return;
    int f = threadIdx.x;           // 0..127
    int end = min(c0 + PCH, N);
    int cur = batch[c0];
    float acc = 0.f;
    for (int v = c0; v < end; ++v) {
        int b = batch[v];          // block-uniform
        if (b != cur) {
            atomicAdd(&pooled[cur * 128 + f], acc);
            acc = 0.f;
            cur = b;
        }
        acc += __bfloat162float(h[(size_t)v * 128 + f]);
    }
    atomicAdd(&pooled[cur * 128 + f], acc);
}

// -------- stage 2: divide by counts --------
__global__ void pool_div(const int* __restrict__ gstart, int G, float* __restrict__ pooled) {
    int t = blockIdx.x * blockDim.x + threadIdx.x;
    int gg = t >> 7;
    if (gg >= G) return;
    int f = t & 127;
    int c = gstart[gg + 1] - gstart[gg];
    pooled[gg * 128 + f] /= (float)(c > 0 ? c : 1);
}

// -------- MLP head (fp32, tiny) --------
__global__ __launch_bounds__(256)
void mlp1_k(const float* __restrict__ pooled, const float* __restrict__ Wm1,
            const float* __restrict__ bm1, float* __restrict__ out1)
{
    __shared__ float Ps[128];
    int gg = blockIdx.x, j = threadIdx.x;
    if (j < 128) Ps[j] = pooled[gg * 128 + j];
    __syncthreads();
    float s = 0.f;
#pragma unroll 4
    for (int k = 0; k < 128; ++k) s = fmaf(Ps[k], Wm1[k * 256 + j], s);
    s += bm1[j];
    out1[gg * 256 + j] = fmaxf(s, 0.f);
}

__global__ __launch_bounds__(768)
void mlp2_k(const float* __restrict__ out1, const float* __restrict__ Wm2,
            const float* __restrict__ bm2, float* __restrict__ out)
{
    __shared__ float Os[256];
    int gg = blockIdx.x, j = threadIdx.x;
    if (j < 256) Os[j] = out1[gg * 256 + j];
    __syncthreads();
    float s = 0.f;
#pragma unroll 4
    for (int k = 0; k < 256; ++k) s = fmaf(Os[k], Wm2[k * 768 + j], s);
    s += bm2[j];
    out[gg * 768 + j] = s;
}

extern "C" void kernel_launch(void* const* d_in, const int* in_sizes, int n_in,
                              void* d_out, int out_size, void* d_ws, size_t ws_size,
                              hipStream_t stream)
{
    const float* x     = (const float*)d_in[0];
    const int*   ei    = (const int*)d_in[1];   // [2,E] int32: src row then dst row
    const int*   batch = (const int*)d_in[2];
    const float *W1 = (const float*)d_in[3],  *bb1 = (const float*)d_in[4];
    const float *W2 = (const float*)d_in[5],  *bb2 = (const float*)d_in[6];
    const float *W3 = (const float*)d_in[7],  *bb3 = (const float*)d_in[8];
    const float *Wm1 = (const float*)d_in[9],  *bm1 = (const float*)d_in[10];
    const float *Wm2 = (const float*)d_in[11], *bm2 = (const float*)d_in[12];

    const int N = in_sizes[2];        // 50000
    const int E = in_sizes[1] / 2;    // 800000
    const int G = out_size / 768;     // 256

    char* wp = (char*)d_ws;
    bf16* bufX   = (bf16*)wp;  wp += (size_t)N * 128 * 2;   // 12.8 MB
    bf16* bufG   = (bf16*)wp;  wp += (size_t)N * 128 * 2;   // 12.8 MB
    bf16* bufH   = (bf16*)wp;  wp += (size_t)N * 128 * 2;   // 12.8 MB
    int*  col    = (int*)wp;   wp += (size_t)E * 4;         // 3.2 MB
    int*  rowptr = (int*)wp;   wp += (size_t)(N + 1) * 4;
    int*  cursor = (int*)wp;   wp += (size_t)N * 4;
    int*  deg    = (int*)wp;   wp += (size_t)N * 4;
    float* dinv  = (float*)wp; wp += (size_t)N * 4;
    int*  gstart = (int*)wp;   wp += (size_t)(G + 1) * 4;
    float* pooled= (float*)wp; wp += (size_t)G * 128 * 4;
    float* out1  = (float*)wp; wp += (size_t)G * 256 * 4;
    int*  bsum   = (int*)wp;   wp += 256 * 4;

    hipMemsetAsync(deg, 0, (size_t)N * 4, stream);
    hipMemsetAsync(cursor, 0, (size_t)N * 4, stream);
    hipMemsetAsync(pooled, 0, (size_t)G * 128 * 4, stream);

    const int SB = (N + 255) / 256;

    // graph structure + input cast
    hist_deg<<<(E + 255) / 256, 256, 0, stream>>>(ei, E, deg);
    dinv_k<<<(N + 255) / 256, 256, 0, stream>>>(deg, N, dinv);
    scan1<<<SB, 256, 0, stream>>>(deg, N, rowptr, bsum);
    scan2<<<1, 256, 0, stream>>>(bsum, SB, N, rowptr);
    scan3<<<SB, 256, 0, stream>>>(N, bsum, rowptr);
    fill_col<<<(E + 255) / 256, 256, 0, stream>>>(ei, E, rowptr, cursor, col);
    bounds_k<<<(N + 255) / 256, 256, 0, stream>>>(batch, N, G, gstart);
    cast_k<<<(N * 128 + 255) / 256, 256, 0, stream>>>(x, N * 128, bufX);

    const int gemm_grid   = (N + 63) / 64;
    const int gather_grid = (N + 3) / 4;

    // layer 1: bufX -> bufG -> bufH
    gemm_mfma<<<gemm_grid, 256, 0, stream>>>(bufX, W1, dinv, N, bufG);
    gather16<<<gather_grid, 256, 0, stream>>>(bufG, rowptr, col, dinv, bb1, N, 1, bufH);
    // layer 2: bufH -> bufG -> bufX (reuse)
    gemm_mfma<<<gemm_grid, 256, 0, stream>>>(bufH, W2, dinv, N, bufG);
    gather16<<<gather_grid, 256, 0, stream>>>(bufG, rowptr, col, dinv, bb2, N, 1, bufX);
    // layer 3 (no relu): bufX -> bufG -> bufH
    gemm_mfma<<<gemm_grid, 256, 0, stream>>>(bufX, W3, dinv, N, bufG);
    gather16<<<gather_grid, 256, 0, stream>>>(bufG, rowptr, col, dinv, bb3, N, 0, bufH);

    // parallel mean pool
    pool_part<<<(N + PCH - 1) / PCH, 128, 0, stream>>>(bufH, batch, N, pooled);
    pool_div<<<(G * 128 + 255) / 256, 256, 0, stream>>>(gstart, G, pooled);

    // MLP head
    mlp1_k<<<G, 256, 0, stream>>>(pooled, Wm1, bm1, out1);
    mlp2_k<<<G, 768, 0, stream>>>(out1, Wm2, bm2, (float*)d_out);
}